// Round 3
// baseline (1449.147 us; speedup 1.0000x reference)
//
#include <hip/hip_runtime.h>

#define N_NODES 100000
#define N_EDGES 1600000
#define D_IN 256
#define D_OUT 128

#define NODES_PER_BKT 32
#define N_BKTS (N_NODES / NODES_PER_BKT)     // 3125 exactly
#define BCAP 1024                            // mean 512, sigma ~23 -> safe

typedef __attribute__((ext_vector_type(8))) short bf16x8;
typedef __attribute__((ext_vector_type(4))) float f32x4;

__device__ __forceinline__ unsigned short f2bf(float f) {
    unsigned u = __float_as_uint(f);
    u += 0x7FFF + ((u >> 16) & 1);          // round-to-nearest-even
    return (unsigned short)(u >> 16);
}

// ---------------------------------------------------------------------------
// prep: W[256][128] f32 -> Wt[128][256] bf16 (col-major), and zero bucket
// counters (ws is re-poisoned 0xAA before every timed launch).
// ---------------------------------------------------------------------------
__global__ void prep_kernel(const float* __restrict__ W,
                            unsigned short* __restrict__ Wt,
                            int* __restrict__ bcount) {
    int idx = blockIdx.x * 256 + threadIdx.x;      // grid covers 32768
    if (idx < D_OUT * D_IN) {
        int c = idx >> 8;          // 0..127
        int k = idx & 255;         // 0..255
        Wt[idx] = f2bf(W[(size_t)k * D_OUT + c]);
    }
    if (idx < N_BKTS) bcount[idx] = 0;
}

// ---------------------------------------------------------------------------
// support(bf16) = x @ W via bf16 MFMA 16x16x32. One wave: 16 rows x 128 cols.
// ---------------------------------------------------------------------------
__global__ __launch_bounds__(256) void gemm_mfma_kernel(
        const float* __restrict__ x,
        const unsigned short* __restrict__ Wt,
        unsigned short* __restrict__ supb) {
    int wid = (int)((blockIdx.x * blockDim.x + threadIdx.x) >> 6);
    int lane = threadIdx.x & 63;
    if (wid >= N_NODES / 16) return;        // 6250 waves exactly
    int r0 = wid * 16;
    int rowA = r0 + (lane & 15);
    int kgrp = (lane >> 4) * 8;             // 0,8,16,24

    f32x4 acc[8];
#pragma unroll
    for (int t = 0; t < 8; ++t) acc[t] = (f32x4){0.f, 0.f, 0.f, 0.f};

    const float* xrow = x + (size_t)rowA * D_IN + kgrp;
    int colbase = lane & 15;

#pragma unroll
    for (int ks = 0; ks < 8; ++ks) {
        int k0 = ks * 32;
        float4 a0 = *(const float4*)(xrow + k0);
        float4 a1 = *(const float4*)(xrow + k0 + 4);
        bf16x8 afrag;
        afrag[0] = (short)f2bf(a0.x); afrag[1] = (short)f2bf(a0.y);
        afrag[2] = (short)f2bf(a0.z); afrag[3] = (short)f2bf(a0.w);
        afrag[4] = (short)f2bf(a1.x); afrag[5] = (short)f2bf(a1.y);
        afrag[6] = (short)f2bf(a1.z); afrag[7] = (short)f2bf(a1.w);
#pragma unroll
        for (int t = 0; t < 8; ++t) {
            bf16x8 bfrag = *(const bf16x8*)(Wt + (size_t)(t * 16 + colbase) * D_IN
                                               + k0 + kgrp);
            acc[t] = __builtin_amdgcn_mfma_f32_16x16x32_bf16(afrag, bfrag,
                                                             acc[t], 0, 0, 0);
        }
    }

    int crow = r0 + (lane >> 4) * 4;
    int ccol = lane & 15;
#pragma unroll
    for (int t = 0; t < 8; ++t) {
#pragma unroll
        for (int j = 0; j < 4; ++j)
            supb[(size_t)(crow + j) * D_OUT + t * 16 + ccol] = f2bf(acc[t][j]);
    }
}

// ---------------------------------------------------------------------------
// binA: partition edges into buckets of 32 dst-nodes.
// staging tuple: {src | (dst&31)<<17, weight_bits}. Cursor-contiguous writes.
// ---------------------------------------------------------------------------
__global__ __launch_bounds__(256) void binA_kernel(
        const int* __restrict__ src,
        const int* __restrict__ dst,
        const float* __restrict__ ew,
        int* __restrict__ bcount,
        int2* __restrict__ staging) {
    int e = blockIdx.x * 256 + threadIdx.x;
    if (e >= N_EDGES) return;
    int d = dst[e];
    int bkt = d >> 5;
    int pos = atomicAdd(&bcount[bkt], 1);
    if (pos < BCAP)
        staging[(size_t)bkt * BCAP + pos] =
            make_int2(src[e] | ((d & 31) << 17), __float_as_int(ew[e]));
}

// ---------------------------------------------------------------------------
// bgather: one block per bucket. 16 KB LDS f32 accumulator (32 nodes x 128ch,
// channels de-interleaved: even ch at slots [0,64), odd at [64,128) so
// ds_add addresses are stride-1 across lanes -> free 2-way bank pattern).
// out[n] = b + sum_e w_e * support[src_e]
// ---------------------------------------------------------------------------
__global__ __launch_bounds__(512) void bgather_kernel(
        const unsigned short* __restrict__ supb,
        const int2* __restrict__ staging,
        const int* __restrict__ bcount,
        const float* __restrict__ b,
        float* __restrict__ out) {
    __shared__ float acc[NODES_PER_BKT * 128];
    int tid = threadIdx.x;
    int bkt = blockIdx.x;

    for (int i = tid; i < NODES_PER_BKT * 128; i += 512) acc[i] = 0.f;
    __syncthreads();

    int cnt = bcount[bkt];
    if (cnt > BCAP) cnt = BCAP;
    int wave = tid >> 6, lane = tid & 63;
    const int2* sg = staging + (size_t)bkt * BCAP;

    for (int e = wave; e < cnt; e += 8) {
        int2 t = sg[e];                       // wave-uniform broadcast load
        int sidx = t.x & 0x1FFFF;
        int dloc = t.x >> 17;
        float w = __int_as_float(t.y);
        unsigned pair = *(const unsigned*)(supb + (size_t)sidx * D_OUT + lane * 2);
        float v0 = __uint_as_float(pair << 16);            // even channel 2*lane
        float v1 = __uint_as_float(pair & 0xFFFF0000u);    // odd channel 2*lane+1
        float* ap = acc + dloc * 128;
        atomicAdd(ap + lane, v0 * w);          // slot lane      <- ch 2*lane
        atomicAdd(ap + 64 + lane, v1 * w);     // slot 64+lane   <- ch 2*lane+1
    }
    __syncthreads();

    int node0 = bkt * NODES_PER_BKT;
    for (int i = tid; i < NODES_PER_BKT * 128; i += 512) {
        int r = i >> 7;
        int s = i & 127;
        int c = (s < 64) ? (2 * s) : (2 * (s - 64) + 1);
        out[(size_t)(node0 + r) * D_OUT + c] = acc[i] + b[c];
    }
}

// ---------------------------------------------------------------------------
extern "C" void kernel_launch(void* const* d_in, const int* in_sizes, int n_in,
                              void* d_out, int out_size, void* d_ws, size_t ws_size,
                              hipStream_t stream) {
    const float* x   = (const float*)d_in[0];
    const int* esrc  = (const int*)d_in[1];
    const int* edst  = (const int*)d_in[2];
    const float* ew  = (const float*)d_in[3];
    const float* W   = (const float*)d_in[4];
    const float* b   = (const float*)d_in[5];
    float* out = (float*)d_out;

    // workspace layout (~51.3 MB)
    uint8_t* w8 = (uint8_t*)d_ws;
    unsigned short* supb = (unsigned short*)w8;               // 25,600,000 B
    int2* staging = (int2*)(w8 + 25600000);                   // 25,600,000 B
    int*  bcount  = (int*)(w8 + 51200000);                    //     12,500 B
    unsigned short* Wt = (unsigned short*)(w8 + 51216384);    //     65,536 B

    prep_kernel<<<(D_OUT * D_IN + 255) / 256, 256, 0, stream>>>(W, Wt, bcount);

    {
        int waves = N_NODES / 16;                 // 6250
        int grid = (waves + 3) / 4;               // 4 waves / block
        gemm_mfma_kernel<<<grid, 256, 0, stream>>>(x, Wt, supb);
    }

    binA_kernel<<<(N_EDGES + 255) / 256, 256, 0, stream>>>(esrc, edst, ew,
                                                           bcount, staging);

    bgather_kernel<<<N_BKTS, 512, 0, stream>>>(supb, staging, bcount, b, out);
}

// Round 4
// 417.898 us; speedup vs baseline: 3.4677x; 3.4677x over previous
//
#include <hip/hip_runtime.h>

#define N_NODES 100000
#define N_EDGES 1600000
#define D_IN 256
#define D_OUT 128

#define NODES_PER_BKT 32
#define N_BKTS (N_NODES / NODES_PER_BKT)     // 3125 exactly
#define BCAP 1024                            // mean 512, sigma ~23 -> safe

typedef __attribute__((ext_vector_type(8))) short bf16x8;
typedef __attribute__((ext_vector_type(4))) float f32x4;

__device__ __forceinline__ unsigned short f2bf(float f) {
    unsigned u = __float_as_uint(f);
    u += 0x7FFF + ((u >> 16) & 1);          // round-to-nearest-even
    return (unsigned short)(u >> 16);
}
__device__ __forceinline__ float bflo(unsigned p) {        // low bf16 -> f32
    return __uint_as_float(p << 16);
}
__device__ __forceinline__ float bfhi(unsigned p) {        // high bf16 -> f32
    return __uint_as_float(p & 0xFFFF0000u);
}

// ---------------------------------------------------------------------------
// prep: W[256][128] f32 -> Wt[128][256] bf16 (col-major), zero bucket counters
// ---------------------------------------------------------------------------
__global__ void prep_kernel(const float* __restrict__ W,
                            unsigned short* __restrict__ Wt,
                            int* __restrict__ bcount) {
    int idx = blockIdx.x * 256 + threadIdx.x;      // grid covers 32768
    if (idx < D_OUT * D_IN) {
        int c = idx >> 8;
        int k = idx & 255;
        Wt[idx] = f2bf(W[(size_t)k * D_OUT + c]);
    }
    if (idx < N_BKTS) bcount[idx] = 0;
}

// ---------------------------------------------------------------------------
// support(bf16) = x @ W via bf16 MFMA 16x16x32. One wave: 16 rows x 128 cols.
// ---------------------------------------------------------------------------
__global__ __launch_bounds__(256) void gemm_mfma_kernel(
        const float* __restrict__ x,
        const unsigned short* __restrict__ Wt,
        unsigned short* __restrict__ supb) {
    int wid = (int)((blockIdx.x * blockDim.x + threadIdx.x) >> 6);
    int lane = threadIdx.x & 63;
    if (wid >= N_NODES / 16) return;        // 6250 waves exactly
    int r0 = wid * 16;
    int rowA = r0 + (lane & 15);
    int kgrp = (lane >> 4) * 8;             // 0,8,16,24

    f32x4 acc[8];
#pragma unroll
    for (int t = 0; t < 8; ++t) acc[t] = (f32x4){0.f, 0.f, 0.f, 0.f};

    const float* xrow = x + (size_t)rowA * D_IN + kgrp;
    int colbase = lane & 15;

#pragma unroll
    for (int ks = 0; ks < 8; ++ks) {
        int k0 = ks * 32;
        float4 a0 = *(const float4*)(xrow + k0);
        float4 a1 = *(const float4*)(xrow + k0 + 4);
        bf16x8 afrag;
        afrag[0] = (short)f2bf(a0.x); afrag[1] = (short)f2bf(a0.y);
        afrag[2] = (short)f2bf(a0.z); afrag[3] = (short)f2bf(a0.w);
        afrag[4] = (short)f2bf(a1.x); afrag[5] = (short)f2bf(a1.y);
        afrag[6] = (short)f2bf(a1.z); afrag[7] = (short)f2bf(a1.w);
#pragma unroll
        for (int t = 0; t < 8; ++t) {
            bf16x8 bfrag = *(const bf16x8*)(Wt + (size_t)(t * 16 + colbase) * D_IN
                                               + k0 + kgrp);
            acc[t] = __builtin_amdgcn_mfma_f32_16x16x32_bf16(afrag, bfrag,
                                                             acc[t], 0, 0, 0);
        }
    }

    int crow = r0 + (lane >> 4) * 4;
    int ccol = lane & 15;
#pragma unroll
    for (int t = 0; t < 8; ++t) {
#pragma unroll
        for (int j = 0; j < 4; ++j)
            supb[(size_t)(crow + j) * D_OUT + t * 16 + ccol] = f2bf(acc[t][j]);
    }
}

// ---------------------------------------------------------------------------
// binA: partition edges into buckets of 32 dst-nodes via global atomic cursor.
// staging tuple: {src | (dst&31)<<17, weight_bits}
// ---------------------------------------------------------------------------
__global__ __launch_bounds__(256) void binA_kernel(
        const int* __restrict__ src,
        const int* __restrict__ dst,
        const float* __restrict__ ew,
        int* __restrict__ bcount,
        int2* __restrict__ staging) {
    int e = blockIdx.x * 256 + threadIdx.x;
    if (e >= N_EDGES) return;
    int d = dst[e];
    int bkt = d >> 5;
    int pos = atomicAdd(&bcount[bkt], 1);
    if (pos < BCAP)
        staging[(size_t)bkt * BCAP + pos] =
            make_int2(src[e] | ((d & 31) << 17), __float_as_int(ew[e]));
}

// ---------------------------------------------------------------------------
// sgather: one block (512 thr) per bucket.
//  Phase A: stage tuples via regs, LDS histogram of dloc (32 keys)
//  Phase B: wave-parallel exclusive scan of 32 counters
//  Phase C: scatter tuples into sorted[] (node-grouped) via LDS cursors
//  Phase D: wave w accumulates nodes 4w..4w+3 in registers (lane = 2 ch),
//           4x-unrolled independent supb loads; biased coalesced writeout.
// ---------------------------------------------------------------------------
__global__ __launch_bounds__(512) void sgather_kernel(
        const unsigned short* __restrict__ supb,
        const int2* __restrict__ staging,
        const int* __restrict__ bcount,
        const float* __restrict__ b,
        float* __restrict__ out) {
    __shared__ int2 sorted[BCAP];
    __shared__ int hist[32];
    __shared__ int cursor[32];
    __shared__ int base[33];

    int tid = threadIdx.x;
    int bkt = blockIdx.x;

    if (tid < 32) hist[tid] = 0;
    __syncthreads();

    int cnt = bcount[bkt];
    if (cnt > BCAP) cnt = BCAP;
    const int2* sg = staging + (size_t)bkt * BCAP;

    // Phase A: load my (<=2) tuples, histogram
    int2 mine0, mine1;
    int dl0 = -1, dl1 = -1;
    if (tid < cnt) {
        mine0 = sg[tid];
        dl0 = (mine0.x >> 17) & 31;
        atomicAdd(&hist[dl0], 1);
    }
    if (tid + 512 < cnt) {
        mine1 = sg[tid + 512];
        dl1 = (mine1.x >> 17) & 31;
        atomicAdd(&hist[dl1], 1);
    }
    __syncthreads();

    // Phase B: exclusive scan of hist -> base[0..32], cursor = start
    if (tid < 64) {
        int l = tid;
        int v = (l < 32) ? hist[l] : 0;
#pragma unroll
        for (int d = 1; d < 32; d <<= 1) {
            int up = __shfl_up(v, d, 64);
            if (l >= d) v += up;
        }
        if (l < 32) {
            base[l + 1] = v;
            cursor[l] = v - hist[l];
        }
        if (l == 0) base[0] = 0;
    }
    __syncthreads();

    // Phase C: scatter into node-grouped order
    if (dl0 >= 0) {
        int pos = atomicAdd(&cursor[dl0], 1);
        sorted[pos] = mine0;
    }
    if (dl1 >= 0) {
        int pos = atomicAdd(&cursor[dl1], 1);
        sorted[pos] = mine1;
    }
    __syncthreads();

    // Phase D: register accumulation, 4 nodes per wave
    int wave = tid >> 6, lane = tid & 63;
    float2 bv = ((const float2*)b)[lane];
    int node0 = bkt * NODES_PER_BKT;

#pragma unroll
    for (int jj = 0; jj < 4; ++jj) {
        int j = wave * 4 + jj;
        int s = base[j], t = base[j + 1];
        float ax = 0.f, ay = 0.f;
        int e = s;
        for (; e + 3 < t; e += 4) {
            int2 t0 = sorted[e];
            int2 t1 = sorted[e + 1];
            int2 t2 = sorted[e + 2];
            int2 t3 = sorted[e + 3];
            unsigned p0 = *(const unsigned*)(supb + (size_t)(t0.x & 0x1FFFF) * D_OUT + 2 * lane);
            unsigned p1 = *(const unsigned*)(supb + (size_t)(t1.x & 0x1FFFF) * D_OUT + 2 * lane);
            unsigned p2 = *(const unsigned*)(supb + (size_t)(t2.x & 0x1FFFF) * D_OUT + 2 * lane);
            unsigned p3 = *(const unsigned*)(supb + (size_t)(t3.x & 0x1FFFF) * D_OUT + 2 * lane);
            float w0 = __int_as_float(t0.y);
            float w1 = __int_as_float(t1.y);
            float w2 = __int_as_float(t2.y);
            float w3 = __int_as_float(t3.y);
            ax += w0 * bflo(p0) + w1 * bflo(p1) + w2 * bflo(p2) + w3 * bflo(p3);
            ay += w0 * bfhi(p0) + w1 * bfhi(p1) + w2 * bfhi(p2) + w3 * bfhi(p3);
        }
        for (; e < t; ++e) {
            int2 t0 = sorted[e];
            unsigned p0 = *(const unsigned*)(supb + (size_t)(t0.x & 0x1FFFF) * D_OUT + 2 * lane);
            float w0 = __int_as_float(t0.y);
            ax += w0 * bflo(p0);
            ay += w0 * bfhi(p0);
        }
        ((float2*)(out + (size_t)(node0 + j) * D_OUT))[lane] =
            make_float2(ax + bv.x, ay + bv.y);
    }
}

// ---------------------------------------------------------------------------
extern "C" void kernel_launch(void* const* d_in, const int* in_sizes, int n_in,
                              void* d_out, int out_size, void* d_ws, size_t ws_size,
                              hipStream_t stream) {
    const float* x   = (const float*)d_in[0];
    const int* esrc  = (const int*)d_in[1];
    const int* edst  = (const int*)d_in[2];
    const float* ew  = (const float*)d_in[3];
    const float* W   = (const float*)d_in[4];
    const float* b   = (const float*)d_in[5];
    float* out = (float*)d_out;

    // workspace layout (~51.3 MB)
    uint8_t* w8 = (uint8_t*)d_ws;
    unsigned short* supb = (unsigned short*)w8;               // 25,600,000 B
    int2* staging = (int2*)(w8 + 25600000);                   // 25,600,000 B
    int*  bcount  = (int*)(w8 + 51200000);                    //     12,500 B
    unsigned short* Wt = (unsigned short*)(w8 + 51216384);    //     65,536 B

    prep_kernel<<<(D_OUT * D_IN + 255) / 256, 256, 0, stream>>>(W, Wt, bcount);

    {
        int waves = N_NODES / 16;                 // 6250
        int grid = (waves + 3) / 4;               // 4 waves / block
        gemm_mfma_kernel<<<grid, 256, 0, stream>>>(x, Wt, supb);
    }

    binA_kernel<<<(N_EDGES + 255) / 256, 256, 0, stream>>>(esrc, edst, ew,
                                                           bcount, staging);

    sgather_kernel<<<N_BKTS, 512, 0, stream>>>(supb, staging, bcount, b, out);
}

// Round 6
// 329.778 us; speedup vs baseline: 4.3943x; 1.2672x over previous
//
#include <hip/hip_runtime.h>

#define N_NODES 100000
#define N_EDGES 1600000
#define D_IN 256
#define D_OUT 128

#define NPB 256                                   // nodes per bin
#define NB 391                                    // ceil(N_NODES / NPB)
#define REGION 4864                               // bin cap (mean 4096, 12 sigma)
#define CHUNK 4096                                // edges per binC block
#define NCHUNK ((N_EDGES + CHUNK - 1) / CHUNK)    // 391

typedef __attribute__((ext_vector_type(8))) short bf16x8;
typedef __attribute__((ext_vector_type(4))) float f32x4;

__device__ __forceinline__ unsigned short f2bf(float f) {
    unsigned u = __float_as_uint(f);
    u += 0x7FFF + ((u >> 16) & 1);          // round-to-nearest-even
    return (unsigned short)(u >> 16);
}
__device__ __forceinline__ float bflo(unsigned p) { return __uint_as_float(p << 16); }
__device__ __forceinline__ float bfhi(unsigned p) { return __uint_as_float(p & 0xFFFF0000u); }

// ---------------------------------------------------------------------------
// prep: W[256][128] f32 -> Wt[128][256] bf16 (col-major), zero bin cursors
// ---------------------------------------------------------------------------
__global__ void prep_kernel(const float* __restrict__ W,
                            unsigned short* __restrict__ Wt,
                            int* __restrict__ gcursor) {
    int idx = blockIdx.x * 256 + threadIdx.x;      // grid covers 32768
    if (idx < D_OUT * D_IN) {
        int c = idx >> 8;
        int k = idx & 255;
        Wt[idx] = f2bf(W[(size_t)k * D_OUT + c]);
    }
    if (idx < NB) gcursor[idx] = 0;
}

// ---------------------------------------------------------------------------
// support(bf16) = x @ W via bf16 MFMA 16x16x32. One wave: 16 rows x 128 cols.
// Block = 2 waves (6250 waves / 2 = 3125 blocks exactly -> no early return,
// safe __syncthreads). Epilogue: LDS transpose -> coalesced dwordx4 stores
// (the old 2B scattered stores were partial-line traffic).
// ---------------------------------------------------------------------------
__global__ __launch_bounds__(128) void gemm_mfma_kernel(
        const float* __restrict__ x,
        const unsigned short* __restrict__ Wt,
        unsigned short* __restrict__ supb) {
    __shared__ unsigned short tile[2][16 * 136];   // 136 = 128 + 8 pad
    int wid = (int)((blockIdx.x * blockDim.x + threadIdx.x) >> 6);
    int lane = threadIdx.x & 63;
    int r0 = wid * 16;
    int rowA = r0 + (lane & 15);
    int kgrp = (lane >> 4) * 8;             // 0,8,16,24

    f32x4 acc[8];
#pragma unroll
    for (int t = 0; t < 8; ++t) acc[t] = (f32x4){0.f, 0.f, 0.f, 0.f};

    const float* xrow = x + (size_t)rowA * D_IN + kgrp;
    int colbase = lane & 15;

#pragma unroll
    for (int ks = 0; ks < 8; ++ks) {
        int k0 = ks * 32;
        float4 a0 = *(const float4*)(xrow + k0);
        float4 a1 = *(const float4*)(xrow + k0 + 4);
        bf16x8 afrag;
        afrag[0] = (short)f2bf(a0.x); afrag[1] = (short)f2bf(a0.y);
        afrag[2] = (short)f2bf(a0.z); afrag[3] = (short)f2bf(a0.w);
        afrag[4] = (short)f2bf(a1.x); afrag[5] = (short)f2bf(a1.y);
        afrag[6] = (short)f2bf(a1.z); afrag[7] = (short)f2bf(a1.w);
#pragma unroll
        for (int t = 0; t < 8; ++t) {
            bf16x8 bfrag = *(const bf16x8*)(Wt + (size_t)(t * 16 + colbase) * D_IN
                                               + k0 + kgrp);
            acc[t] = __builtin_amdgcn_mfma_f32_16x16x32_bf16(afrag, bfrag,
                                                             acc[t], 0, 0, 0);
        }
    }

    // epilogue: acc -> LDS (bf16) -> coalesced 16B stores
    unsigned short* tl = tile[threadIdx.x >> 6];
    int rgrp = (lane >> 4) * 4;
#pragma unroll
    for (int t = 0; t < 8; ++t)
#pragma unroll
        for (int j = 0; j < 4; ++j)
            tl[(rgrp + j) * 136 + t * 16 + colbase] = f2bf(acc[t][j]);
    __syncthreads();

    int row = lane >> 2;        // 0..15
    int c4 = lane & 3;
#pragma unroll
    for (int u = 0; u < 4; ++u) {
        int col0 = u * 32 + c4 * 8;
        int4 v = *(const int4*)(tl + row * 136 + col0);
        *(int4*)(supb + (size_t)(r0 + row) * D_OUT + col0) = v;
    }
}

// ---------------------------------------------------------------------------
// binC: block-aggregated binning. Block = 512 thr, 4096 edges.
//   LDS counting sort by bin (391 bins) -> 1 global atomic per (bin,block)
//   -> contiguous flush runs (~84B avg). Tuple: {src | dloc<<17, w_bits},
//   dloc = dst & 255 (8 bits, fits: 17+8=25).
// ---------------------------------------------------------------------------
__global__ __launch_bounds__(512) void binC_kernel(
        const int* __restrict__ src,
        const int* __restrict__ dst,
        const float* __restrict__ ew,
        int* __restrict__ gcursor,
        int2* __restrict__ stg) {
    __shared__ int hist[NB];
    __shared__ int startsh[NB];
    __shared__ int cursor[NB];
    __shared__ int gbase[NB];
    __shared__ int scanbuf[512];
    __shared__ short sbin[CHUNK];
    __shared__ int2 stage[CHUNK];

    int tid = threadIdx.x;
    int e0 = blockIdx.x * CHUNK;
    int cn = N_EDGES - e0;
    if (cn > CHUNK) cn = CHUNK;

    for (int i = tid; i < NB; i += 512) hist[i] = 0;
    __syncthreads();

    int2 tup[8];
    int bin[8];
#pragma unroll
    for (int k = 0; k < 8; ++k) {
        int e = e0 + k * 512 + tid;
        bin[k] = -1;
        if (e < N_EDGES) {
            int d = dst[e];
            bin[k] = d >> 8;
            tup[k] = make_int2(src[e] | ((d & 255) << 17), __float_as_int(ew[e]));
            atomicAdd(&hist[bin[k]], 1);
        }
    }
    __syncthreads();

    // exclusive scan of hist[0..NB)
    int v = (tid < NB) ? hist[tid] : 0;
    scanbuf[tid] = v;
    __syncthreads();
#pragma unroll
    for (int d = 1; d < 512; d <<= 1) {
        int t = (tid >= d) ? scanbuf[tid - d] : 0;
        __syncthreads();
        scanbuf[tid] += t;
        __syncthreads();
    }
    if (tid < NB) {
        startsh[tid] = scanbuf[tid] - v;
        cursor[tid] = scanbuf[tid] - v;
    }
    __syncthreads();

    // scatter into bin-sorted LDS stage
#pragma unroll
    for (int k = 0; k < 8; ++k) {
        if (bin[k] >= 0) {
            int pos = atomicAdd(&cursor[bin[k]], 1);
            stage[pos] = tup[k];
            sbin[pos] = (short)bin[k];
        }
    }

    // reserve global space: one atomic per (bin, block)
    if (tid < NB && v > 0)
        gbase[tid] = atomicAdd(&gcursor[tid], v);
    __syncthreads();

    // flush: contiguous runs per bin, coalesced across threads
    for (int i = tid; i < cn; i += 512) {
        int bb = sbin[i];
        int off = gbase[bb] + (i - startsh[bb]);
        if (off < REGION)
            stg[(size_t)bb * REGION + off] = stage[i];
    }
}

// ---------------------------------------------------------------------------
// sgather: one block (512 thr) per 256-node bin.
//  A: histogram dloc (256 keys) from global staging
//  B: exclusive scan -> base/cursor
//  C: re-read staging, scatter into sorted[] (node-grouped, LDS)
//  D: 8 waves x 32 nodes, register accumulate (lane = 2 ch), 4x unroll.
// ---------------------------------------------------------------------------
__global__ __launch_bounds__(512) void sgather_kernel(
        const unsigned short* __restrict__ supb,
        const int2* __restrict__ stg,
        const int* __restrict__ gcursor,
        const float* __restrict__ b,
        float* __restrict__ out) {
    __shared__ int2 sorted[REGION];
    __shared__ int hist2[256];
    __shared__ int base2[257];
    __shared__ int cur2[256];
    __shared__ int scanbuf[512];

    int tid = threadIdx.x;
    int bkt = blockIdx.x;
    int node0 = bkt * NPB;

    if (tid < 256) hist2[tid] = 0;
    __syncthreads();

    int cnt = gcursor[bkt];
    if (cnt > REGION) cnt = REGION;
    const int2* sg = stg + (size_t)bkt * REGION;

    for (int e = tid; e < cnt; e += 512)
        atomicAdd(&hist2[(sg[e].x >> 17) & 255], 1);
    __syncthreads();

    int v = (tid < 256) ? hist2[tid] : 0;
    scanbuf[tid] = v;
    __syncthreads();
#pragma unroll
    for (int d = 1; d < 512; d <<= 1) {
        int t = (tid >= d) ? scanbuf[tid - d] : 0;
        __syncthreads();
        scanbuf[tid] += t;
        __syncthreads();
    }
    if (tid < 256) {
        base2[tid] = scanbuf[tid] - v;
        cur2[tid] = scanbuf[tid] - v;
    }
    if (tid == 0) base2[256] = cnt;
    __syncthreads();

    for (int e = tid; e < cnt; e += 512) {
        int2 t = sg[e];
        int pos = atomicAdd(&cur2[(t.x >> 17) & 255], 1);
        sorted[pos] = t;
    }
    __syncthreads();

    int wave = tid >> 6, lane = tid & 63;
    float2 bv = ((const float2*)b)[lane];

    for (int jj = 0; jj < 32; ++jj) {
        int j = wave * 32 + jj;
        int node = node0 + j;
        if (node >= N_NODES) break;
        int s = base2[j], t = base2[j + 1];
        float ax = 0.f, ay = 0.f;
        int e = s;
        for (; e + 3 < t; e += 4) {
            int2 t0 = sorted[e];
            int2 t1 = sorted[e + 1];
            int2 t2 = sorted[e + 2];
            int2 t3 = sorted[e + 3];
            unsigned p0 = *(const unsigned*)(supb + (size_t)(t0.x & 0x1FFFF) * D_OUT + 2 * lane);
            unsigned p1 = *(const unsigned*)(supb + (size_t)(t1.x & 0x1FFFF) * D_OUT + 2 * lane);
            unsigned p2 = *(const unsigned*)(supb + (size_t)(t2.x & 0x1FFFF) * D_OUT + 2 * lane);
            unsigned p3 = *(const unsigned*)(supb + (size_t)(t3.x & 0x1FFFF) * D_OUT + 2 * lane);
            float w0 = __int_as_float(t0.y);
            float w1 = __int_as_float(t1.y);
            float w2 = __int_as_float(t2.y);
            float w3 = __int_as_float(t3.y);
            ax += w0 * bflo(p0) + w1 * bflo(p1) + w2 * bflo(p2) + w3 * bflo(p3);
            ay += w0 * bfhi(p0) + w1 * bfhi(p1) + w2 * bfhi(p2) + w3 * bfhi(p3);
        }
        for (; e < t; ++e) {
            int2 t0 = sorted[e];
            unsigned p0 = *(const unsigned*)(supb + (size_t)(t0.x & 0x1FFFF) * D_OUT + 2 * lane);
            float w0 = __int_as_float(t0.y);
            ax += w0 * bflo(p0);
            ay += w0 * bfhi(p0);
        }
        ((float2*)(out + (size_t)node * D_OUT))[lane] =
            make_float2(ax + bv.x, ay + bv.y);
    }
}

// ---------------------------------------------------------------------------
extern "C" void kernel_launch(void* const* d_in, const int* in_sizes, int n_in,
                              void* d_out, int out_size, void* d_ws, size_t ws_size,
                              hipStream_t stream) {
    const float* x   = (const float*)d_in[0];
    const int* esrc  = (const int*)d_in[1];
    const int* edst  = (const int*)d_in[2];
    const float* ew  = (const float*)d_in[3];
    const float* W   = (const float*)d_in[4];
    const float* b   = (const float*)d_in[5];
    float* out = (float*)d_out;

    // workspace layout (~40.9 MB)
    uint8_t* w8 = (uint8_t*)d_ws;
    unsigned short* supb = (unsigned short*)w8;               // 25,600,000 B
    int2* stg     = (int2*)(w8 + 25600000);                   // 15,214,592 B
    int*  gcursor = (int*)(w8 + 40814592);                    //      1,564 B
    unsigned short* Wt = (unsigned short*)(w8 + 40816640);    //     65,536 B

    prep_kernel<<<(D_OUT * D_IN + 255) / 256, 256, 0, stream>>>(W, Wt, gcursor);

    gemm_mfma_kernel<<<3125, 128, 0, stream>>>(x, Wt, supb);

    binC_kernel<<<NCHUNK, 512, 0, stream>>>(esrc, edst, ew, gcursor, stg);

    sgather_kernel<<<NB, 512, 0, stream>>>(supb, stg, gcursor, b, out);
}

// Round 7
// 301.847 us; speedup vs baseline: 4.8009x; 1.0925x over previous
//
#include <hip/hip_runtime.h>

#define N_NODES 100000
#define N_EDGES 1600000
#define D_IN 256
#define D_OUT 128

#define NPB 128                                   // nodes per bin
#define NB 782                                    // ceil(N_NODES / NPB)
#define REGION 2432                               // bin cap (mean 2046, +8.5 sigma)
#define CHUNK 4096                                // edges per binC block
#define NCHUNK 391                                // ceil(N_EDGES / CHUNK)
#define GEMM_BLOCKS 782                           // 128 rows per block (8 waves x 16)

typedef __attribute__((ext_vector_type(8))) short bf16x8;
typedef __attribute__((ext_vector_type(4))) float f32x4;

__device__ __forceinline__ unsigned short f2bf(float f) {
    unsigned u = __float_as_uint(f);
    u += 0x7FFF + ((u >> 16) & 1);          // round-to-nearest-even
    return (unsigned short)(u >> 16);
}
__device__ __forceinline__ float bflo(unsigned p) { return __uint_as_float(p << 16); }
__device__ __forceinline__ float bfhi(unsigned p) { return __uint_as_float(p & 0xFFFF0000u); }

// ---------------------------------------------------------------------------
// prep: W[256][128] f32 -> Wt[128][256] bf16 (col-major), zero bin cursors
// ---------------------------------------------------------------------------
__global__ void prep_kernel(const float* __restrict__ W,
                            unsigned short* __restrict__ Wt,
                            int* __restrict__ gcursor) {
    int idx = blockIdx.x * 256 + threadIdx.x;      // grid covers 32768
    if (idx < D_OUT * D_IN) {
        int c = idx >> 8;
        int k = idx & 255;
        Wt[idx] = f2bf(W[(size_t)k * D_OUT + c]);
    }
    if (idx < NB) gcursor[idx] = 0;
}

// ---------------------------------------------------------------------------
// fused: blockIdx < NCHUNK -> binC (block-aggregated edge binning)
//        else              -> gemm (bf16 MFMA, 128 rows per block)
// The two halves are independent; fusing overlaps binC's store/atomic phase
// with gemm's BW/MFMA phase (same-stream kernels otherwise serialize).
// ---------------------------------------------------------------------------
struct BinSmem {
    int hist[NB];          // per-bin count
    int startsh[NB];       // local exclusive start in stage[]
    int adj[NB];           // scatter cursor, then (gbase - startsh)
    int scanbuf[512];
    short sbin[CHUNK];
    int2 stage[CHUNK];
};                          // 52,392 B
struct GemmSmem {
    unsigned short tile[8][16 * 136];   // 34,816 B (136 = 128 + 8 pad)
};
union FusedSmem { BinSmem b; GemmSmem g; };

__global__ __launch_bounds__(512) void fused_kernel(
        const float* __restrict__ x,
        const unsigned short* __restrict__ Wt,
        unsigned short* __restrict__ supb,
        const int* __restrict__ src,
        const int* __restrict__ dst,
        const float* __restrict__ ew,
        int* __restrict__ gcursor,
        int2* __restrict__ stg) {
    __shared__ FusedSmem sm;
    int tid = threadIdx.x;

    if (blockIdx.x < NCHUNK) {
        // ------------------------------ binC ------------------------------
        BinSmem& bs = sm.b;
        int e0 = blockIdx.x * CHUNK;
        int cn = N_EDGES - e0;
        if (cn > CHUNK) cn = CHUNK;

        for (int i = tid; i < NB; i += 512) bs.hist[i] = 0;
        __syncthreads();

        int2 tup[8];
        int bin[8];
#pragma unroll
        for (int k = 0; k < 8; ++k) {
            int e = e0 + k * 512 + tid;
            bin[k] = -1;
            if (e < N_EDGES) {
                int d = dst[e];
                bin[k] = d >> 7;
                tup[k] = make_int2(src[e] | ((d & 127) << 17),
                                   __float_as_int(ew[e]));
                atomicAdd(&bs.hist[bin[k]], 1);
            }
        }
        __syncthreads();

        // exclusive scan over NB=782 bins (two 512-wide passes)
        int total0 = 0;
        for (int half = 0; half < 2; ++half) {
            int idx = half * 512 + tid;
            int v = (idx < NB) ? bs.hist[idx] : 0;
            bs.scanbuf[tid] = v;
            __syncthreads();
            for (int d = 1; d < 512; d <<= 1) {
                int t = (tid >= d) ? bs.scanbuf[tid - d] : 0;
                __syncthreads();
                bs.scanbuf[tid] += t;
                __syncthreads();
            }
            if (idx < NB) {
                int st = total0 + bs.scanbuf[tid] - v;
                bs.startsh[idx] = st;
                bs.adj[idx] = st;
            }
            total0 += bs.scanbuf[511];
            __syncthreads();
        }

        // scatter into bin-sorted LDS stage
#pragma unroll
        for (int k = 0; k < 8; ++k) {
            if (bin[k] >= 0) {
                int pos = atomicAdd(&bs.adj[bin[k]], 1);
                bs.stage[pos] = tup[k];
                bs.sbin[pos] = (short)bin[k];
            }
        }
        __syncthreads();

        // reserve global space (1 atomic per non-empty bin per block);
        // adj becomes (gbase - startsh) so flush offset = adj[bb] + i
        for (int i = tid; i < NB; i += 512) {
            int hv = bs.hist[i];
            if (hv > 0)
                bs.adj[i] = atomicAdd(&gcursor[i], hv) - bs.startsh[i];
        }
        __syncthreads();

        // flush: contiguous per-bin runs, coalesced across threads
        for (int i = tid; i < cn; i += 512) {
            int bb = bs.sbin[i];
            int off = bs.adj[bb] + i;
            if (off < REGION)
                stg[(size_t)bb * REGION + off] = bs.stage[i];
        }
    } else {
        // ------------------------------ gemm ------------------------------
        GemmSmem& gs = sm.g;
        int gb = blockIdx.x - NCHUNK;
        int widl = tid >> 6;                  // 0..7
        int lane = tid & 63;
        int r0 = (gb * 8 + widl) * 16;        // up to 100,080; clamp below
        int rowA = r0 + (lane & 15);
        int rowAc = rowA < N_NODES ? rowA : N_NODES - 1;
        int kgrp = (lane >> 4) * 8;           // 0,8,16,24

        f32x4 acc[8];
#pragma unroll
        for (int t = 0; t < 8; ++t) acc[t] = (f32x4){0.f, 0.f, 0.f, 0.f};

        const float* xrow = x + (size_t)rowAc * D_IN + kgrp;
        int colbase = lane & 15;

#pragma unroll
        for (int ks = 0; ks < 8; ++ks) {
            int k0 = ks * 32;
            float4 a0 = *(const float4*)(xrow + k0);
            float4 a1 = *(const float4*)(xrow + k0 + 4);
            bf16x8 afrag;
            afrag[0] = (short)f2bf(a0.x); afrag[1] = (short)f2bf(a0.y);
            afrag[2] = (short)f2bf(a0.z); afrag[3] = (short)f2bf(a0.w);
            afrag[4] = (short)f2bf(a1.x); afrag[5] = (short)f2bf(a1.y);
            afrag[6] = (short)f2bf(a1.z); afrag[7] = (short)f2bf(a1.w);
#pragma unroll
            for (int t = 0; t < 8; ++t) {
                bf16x8 bfrag = *(const bf16x8*)(Wt +
                        (size_t)(t * 16 + colbase) * D_IN + k0 + kgrp);
                acc[t] = __builtin_amdgcn_mfma_f32_16x16x32_bf16(afrag, bfrag,
                                                                 acc[t], 0, 0, 0);
            }
        }

        // epilogue: acc -> LDS (bf16) -> coalesced 16B stores.
        // tile[widl] is written and read only by this wave -> no barrier.
        unsigned short* tl = gs.tile[widl];
        int rgrp = (lane >> 4) * 4;
#pragma unroll
        for (int t = 0; t < 8; ++t)
#pragma unroll
            for (int j = 0; j < 4; ++j)
                tl[(rgrp + j) * 136 + t * 16 + colbase] = f2bf(acc[t][j]);

        int row = lane >> 2;        // 0..15
        int c4 = lane & 3;
        int orow = r0 + row;
        if (orow < N_NODES) {
#pragma unroll
            for (int u = 0; u < 4; ++u) {
                int col0 = u * 32 + c4 * 8;
                int4 v = *(const int4*)(tl + row * 136 + col0);
                *(int4*)(supb + (size_t)orow * D_OUT + col0) = v;
            }
        }
    }
}

// ---------------------------------------------------------------------------
// sgather: one block (512 thr) per 128-node bin (782 blocks -> ~3 blocks/CU,
// fully resident). Tuples stashed in statically-indexed registers.
//  A: stash + histogram dloc (128 keys)
//  B: exclusive scan -> base/cursor
//  C: scatter from regs into sorted[] (node-grouped, LDS)
//  D: 8 waves x 16 nodes, register accumulate (lane = 2 ch), 4x unroll.
// ---------------------------------------------------------------------------
__global__ __launch_bounds__(512) void sgather_kernel(
        const unsigned short* __restrict__ supb,
        const int2* __restrict__ stg,
        const int* __restrict__ gcursor,
        const float* __restrict__ b,
        float* __restrict__ out) {
    __shared__ int2 sorted[REGION];          // 19,456 B
    __shared__ int hist2[NPB];
    __shared__ int base2[NPB + 1];
    __shared__ int cur2[NPB];
    __shared__ int scanbuf[512];

    int tid = threadIdx.x;
    int bkt = blockIdx.x;
    int node0 = bkt * NPB;

    if (tid < NPB) hist2[tid] = 0;
    __syncthreads();

    int cnt = gcursor[bkt];
    if (cnt > REGION) cnt = REGION;
    const int2* sg = stg + (size_t)bkt * REGION;

    // Phase A: stash (<=5 tuples/thread, static indices) + histogram
    int2 tp[5];
    int dl[5];
#pragma unroll
    for (int k = 0; k < 5; ++k) {
        int e = tid + k * 512;
        dl[k] = -1;
        if (e < cnt) {
            tp[k] = sg[e];
            dl[k] = (tp[k].x >> 17) & 127;
            atomicAdd(&hist2[dl[k]], 1);
        }
    }
    __syncthreads();

    // Phase B: exclusive scan of 128 counters
    int v = (tid < NPB) ? hist2[tid] : 0;
    scanbuf[tid] = v;
    __syncthreads();
    for (int d = 1; d < NPB; d <<= 1) {
        int t = (tid >= d) ? scanbuf[tid - d] : 0;
        __syncthreads();
        scanbuf[tid] += t;
        __syncthreads();
    }
    if (tid < NPB) {
        base2[tid] = scanbuf[tid] - v;
        cur2[tid] = scanbuf[tid] - v;
    }
    if (tid == 0) base2[NPB] = cnt;
    __syncthreads();

    // Phase C: scatter from registers
#pragma unroll
    for (int k = 0; k < 5; ++k) {
        if (dl[k] >= 0) {
            int pos = atomicAdd(&cur2[dl[k]], 1);
            sorted[pos] = tp[k];
        }
    }
    __syncthreads();

    // Phase D: register accumulation, 16 nodes per wave
    int wave = tid >> 6, lane = tid & 63;
    float2 bv = ((const float2*)b)[lane];

#pragma unroll 1
    for (int jj = 0; jj < 16; ++jj) {
        int j = wave * 16 + jj;
        int node = node0 + j;
        if (node >= N_NODES) break;
        int s = base2[j], t = base2[j + 1];
        float ax = 0.f, ay = 0.f;
        int e = s;
        for (; e + 3 < t; e += 4) {
            int2 t0 = sorted[e];
            int2 t1 = sorted[e + 1];
            int2 t2 = sorted[e + 2];
            int2 t3 = sorted[e + 3];
            unsigned p0 = *(const unsigned*)(supb + (size_t)(t0.x & 0x1FFFF) * D_OUT + 2 * lane);
            unsigned p1 = *(const unsigned*)(supb + (size_t)(t1.x & 0x1FFFF) * D_OUT + 2 * lane);
            unsigned p2 = *(const unsigned*)(supb + (size_t)(t2.x & 0x1FFFF) * D_OUT + 2 * lane);
            unsigned p3 = *(const unsigned*)(supb + (size_t)(t3.x & 0x1FFFF) * D_OUT + 2 * lane);
            float w0 = __int_as_float(t0.y);
            float w1 = __int_as_float(t1.y);
            float w2 = __int_as_float(t2.y);
            float w3 = __int_as_float(t3.y);
            ax += w0 * bflo(p0) + w1 * bflo(p1) + w2 * bflo(p2) + w3 * bflo(p3);
            ay += w0 * bfhi(p0) + w1 * bfhi(p1) + w2 * bfhi(p2) + w3 * bfhi(p3);
        }
        for (; e < t; ++e) {
            int2 t0 = sorted[e];
            unsigned p0 = *(const unsigned*)(supb + (size_t)(t0.x & 0x1FFFF) * D_OUT + 2 * lane);
            float w0 = __int_as_float(t0.y);
            ax += w0 * bflo(p0);
            ay += w0 * bfhi(p0);
        }
        ((float2*)(out + (size_t)node * D_OUT))[lane] =
            make_float2(ax + bv.x, ay + bv.y);
    }
}

// ---------------------------------------------------------------------------
extern "C" void kernel_launch(void* const* d_in, const int* in_sizes, int n_in,
                              void* d_out, int out_size, void* d_ws, size_t ws_size,
                              hipStream_t stream) {
    const float* x   = (const float*)d_in[0];
    const int* esrc  = (const int*)d_in[1];
    const int* edst  = (const int*)d_in[2];
    const float* ew  = (const float*)d_in[3];
    const float* W   = (const float*)d_in[4];
    const float* b   = (const float*)d_in[5];
    float* out = (float*)d_out;

    // workspace layout (~40.9 MB)
    uint8_t* w8 = (uint8_t*)d_ws;
    unsigned short* supb = (unsigned short*)w8;               // 25,600,000 B
    int2* stg     = (int2*)(w8 + 25600000);                   // 15,214,592 B (782*2432*8)
    int*  gcursor = (int*)(w8 + 40814592);                    //      3,128 B
    unsigned short* Wt = (unsigned short*)(w8 + 40818688);    //     65,536 B

    prep_kernel<<<(D_OUT * D_IN + 255) / 256, 256, 0, stream>>>(W, Wt, gcursor);

    fused_kernel<<<NCHUNK + GEMM_BLOCKS, 512, 0, stream>>>(
        x, Wt, supb, esrc, edst, ew, gcursor, stg);

    sgather_kernel<<<NB, 512, 0, stream>>>(supb, stg, gcursor, b, out);
}